// Round 3
// baseline (218.397 us; speedup 1.0000x reference)
//
#include <hip/hip_runtime.h>
#include <stdint.h>

#define S_LEN 1024
#define DDIM  512
#define NBATCH 16

typedef __attribute__((ext_vector_type(8))) short bf16x8;
typedef __attribute__((ext_vector_type(4))) float f32x4;
typedef unsigned short ushort_t;

__device__ __forceinline__ unsigned short f2bf(float x) {
  union { float f; uint32_t u; } v; v.f = x;
  return (unsigned short)((v.u + 0x7fffu + ((v.u >> 16) & 1u)) >> 16);
}
__device__ __forceinline__ float bf2f(unsigned short h) {
  union { float f; uint32_t u; } v; v.u = ((uint32_t)h) << 16;
  return v.f;
}

__device__ __forceinline__ void gload16(const void* g, void* l) {
  __builtin_amdgcn_global_load_lds(
      (const __attribute__((address_space(1))) void*)g,
      (__attribute__((address_space(3))) void*)l, 16, 0, 0);
}

// ---------------------------------------------------------------------------
// K1: per-row prep: sj[row] = P[row,:]·wb ; Pbf = bf16(P) ; Qbf = bf16(P*wc)
__global__ __launch_bounds__(256) void prep_rows(
    const float* __restrict__ P, const float* __restrict__ w_atten,
    unsigned short* __restrict__ Pbf, unsigned short* __restrict__ Qbf,
    float* __restrict__ sj) {
  int wave = threadIdx.x >> 6, lane = threadIdx.x & 63;
  int row = blockIdx.x * 4 + wave;
  const float* prow = P + (size_t)row * DDIM;
  float s = 0.f;
#pragma unroll
  for (int h = 0; h < 2; ++h) {
    int d = h * 256 + lane * 4;
    float4 p  = *(const float4*)(prow + d);
    float4 wb = *(const float4*)(w_atten + DDIM + d);
    float4 wc = *(const float4*)(w_atten + 2 * DDIM + d);
    s += p.x * wb.x + p.y * wb.y + p.z * wb.z + p.w * wb.w;
    ushort4 pb, qb;
    pb.x = f2bf(p.x); pb.y = f2bf(p.y); pb.z = f2bf(p.z); pb.w = f2bf(p.w);
    qb.x = f2bf(p.x * wc.x); qb.y = f2bf(p.y * wc.y);
    qb.z = f2bf(p.z * wc.z); qb.w = f2bf(p.w * wc.w);
    *(ushort4*)(Pbf + (size_t)row * DDIM + d) = pb;
    *(ushort4*)(Qbf + (size_t)row * DDIM + d) = qb;
  }
#pragma unroll
  for (int o = 32; o; o >>= 1) s += __shfl_xor(s, o);
  if (lane == 0) sj[row] = s;
}

// ---------------------------------------------------------------------------
// K2: tiled transpose fp32[R][C] -> bf16[C][R]   (64x64 tiles)
__global__ __launch_bounds__(256) void transpose_f2b(
    const float* __restrict__ in, unsigned short* __restrict__ out,
    int R, int C, long inStride, long outStride) {
  __shared__ unsigned short T[64][65];
  in  += (size_t)blockIdx.z * inStride;
  out += (size_t)blockIdx.z * outStride;
  int c0 = blockIdx.x * 64, r0 = blockIdx.y * 64;
  int tx = threadIdx.x & 63, ty = threadIdx.x >> 6;
#pragma unroll
  for (int rr = 0; rr < 16; ++rr) {
    int rl = ty * 16 + rr;
    T[rl][tx] = f2bf(in[(size_t)(r0 + rl) * C + c0 + tx]);
  }
  __syncthreads();
#pragma unroll
  for (int rr = 0; rr < 16; ++rr) {
    int cl = ty * 16 + rr;
    out[(size_t)(c0 + cl) * R + r0 + tx] = T[tx][cl];
  }
}

// ---------------------------------------------------------------------------
// 8-phase 256x256 bf16 NT GEMM (T2+T3+T4+T5), BK=64, 8 waves (2M x 4N).
// C[M][N] = A[M][K(lda)] * Bt[N][K]^T. A2/Ksplit: K-concat source switch.
// LDS 128 KiB: A/B x dbuf x 2 halves of [128][64] bf16, st_16x32-swizzled
// content staged via pre-swizzled GLOBAL source (linear gload_lds dest).
// EPI: 0 plain; 1 +bias[col]; 4 fused MLP (seg=col>>9, tanh/sigmoid).
#define STAGE_A(buf, h, kt_) do { int k0_ = (kt_) * 64; const ushort_t* s_ = A;   \
    if (A2 != nullptr && k0_ >= Ksplit) { s_ = A2; k0_ -= Ksplit; }               \
    ushort_t* d_ = &lds[((buf) * 2 + (h)) * 8192 + w * 1024];                     \
    const ushort_t* g_ = s_ + (size_t)(bm + (h) * 128 + srow) * lda + k0_ + scol; \
    gload16(g_, d_); gload16(g_ + 32, d_ + 512); } while (0)

#define STAGE_B(buf, h, kt_) do { int k0_ = (kt_) * 64;                           \
    ushort_t* d_ = &lds[32768 + ((buf) * 2 + (h)) * 8192 + w * 1024];             \
    const ushort_t* g_ = Bt + (size_t)(bn + (h) * 128 + srow) * K + k0_ + scol;   \
    gload16(g_, d_); gload16(g_ + 32, d_ + 512); } while (0)

#define READ_A(mh) do { const char* ab_ = (const char*)&lds[(cur * 2 + wr) * 8192]; \
    _Pragma("unroll") for (int m_ = 0; m_ < 4; ++m_)                                \
    _Pragma("unroll") for (int ks_ = 0; ks_ < 2; ++ks_)                             \
      af[m_][ks_] = *(const bf16x8*)(ab_ + ((((mh) * 4 + m_) * 2 + ks_) << 10)      \
                                     + rl * 64 + swzc); } while (0)

#define READ_B(nh) do { const char* bb_ = (const char*)&lds[32768 + (cur * 2 + (wc >> 1)) * 8192]; \
    _Pragma("unroll") for (int n_ = 0; n_ < 2; ++n_)                                \
    _Pragma("unroll") for (int ks_ = 0; ks_ < 2; ++ks_)                             \
      bfr[(nh) * 2 + n_][ks_] = *(const bf16x8*)(bb_ +                              \
          ((((wc & 1) * 4 + (nh) * 2 + n_) * 2 + ks_) << 10) + rl * 64 + swzc); } while (0)

#define MFMA_Q(mh, nh) do {                                                       \
    __builtin_amdgcn_s_setprio(1);                                                \
    _Pragma("unroll") for (int m_ = 0; m_ < 4; ++m_)                              \
    _Pragma("unroll") for (int n_ = 0; n_ < 2; ++n_) {                            \
      f32x4 a_ = acc[(mh) * 4 + m_][(nh) * 2 + n_];                               \
      a_ = __builtin_amdgcn_mfma_f32_16x16x32_bf16(af[m_][0], bfr[(nh)*2+n_][0], a_, 0, 0, 0); \
      a_ = __builtin_amdgcn_mfma_f32_16x16x32_bf16(af[m_][1], bfr[(nh)*2+n_][1], a_, 0, 0, 0); \
      acc[(mh) * 4 + m_][(nh) * 2 + n_] = a_; }                                   \
    __builtin_amdgcn_s_setprio(0); } while (0)

#define PHASE_SYNC() do { __builtin_amdgcn_s_barrier();                           \
    asm volatile("s_waitcnt lgkmcnt(0)" ::: "memory");                            \
    __builtin_amdgcn_sched_barrier(0); } while (0)

template<int EPI>
__global__ __launch_bounds__(512, 2) void gemm8(
    const ushort_t* __restrict__ A,
    const ushort_t* __restrict__ A2,
    const ushort_t* __restrict__ Bt,
    ushort_t* __restrict__ C,
    const float* __restrict__ bias,
    const float* __restrict__ bias2,
    const float* __restrict__ bias3,
    int N, int K, int lda, int Ksplit,
    long sAb, long sBb, long sCb, long sBiasb) {
  __shared__ __align__(16) ushort_t lds[65536];   // 128 KiB
  const int t = threadIdx.x, lane = t & 63, w = t >> 6;
  const int wr = w >> 2, wc = w & 3;
  const int z = blockIdx.z;
  A += (size_t)z * sAb;
  if (A2) A2 += (size_t)z * sAb;
  Bt += (size_t)z * sBb;
  C += (size_t)z * sCb;
  if (bias) bias += (size_t)z * sBiasb;
  const int bm = blockIdx.y * 256, bn = blockIdx.x * 256;
  const int NT = K >> 6;

  const int rl = lane & 15;                              // frag row in subtile
  const int swzc = ((lane >> 4) << 4) ^ ((lane & 8) << 2);  // swizzled k-byte
  const int srow = w * 16 + (lane >> 2);                 // staging row in half
  const int scol = ((lane & 3) * 8) ^ ((lane & 32) >> 1);   // pre-swizzled k-col

  f32x4 acc[8][4];
#pragma unroll
  for (int m = 0; m < 8; ++m)
#pragma unroll
    for (int n = 0; n < 4; ++n) acc[m][n] = {0.f, 0.f, 0.f, 0.f};
  bf16x8 af[4][2], bfr[4][2];

  // prologue: A(0) x2 halves, B(0) x2, B(1) x2  (order matters for vmcnt)
  STAGE_A(0, 0, 0); STAGE_A(0, 1, 0);
  STAGE_B(0, 0, 0); STAGE_B(0, 1, 0);
  STAGE_B(1, 0, 1); STAGE_B(1, 1, 1);
  asm volatile("s_waitcnt vmcnt(4)" ::: "memory");   // A(0),B(0) landed
  __builtin_amdgcn_s_barrier();

  for (int kt = 0; kt < NT; ++kt) {
    const int cur = kt & 1, nxt = cur ^ 1;
    // ---- q0: quadrant (m0-3, n0-1)
    READ_A(0); READ_B(0);
    if (kt + 1 < NT) STAGE_A(nxt, 0, kt + 1);
    PHASE_SYNC();
    MFMA_Q(0, 0);
    __builtin_amdgcn_s_barrier();
    // ---- q1: quadrant (m0-3, n2-3)
    READ_B(1);
    if (kt + 1 < NT) STAGE_A(nxt, 1, kt + 1);
    PHASE_SYNC();
    MFMA_Q(0, 1);
    __builtin_amdgcn_s_barrier();
    // ---- q2: quadrant (m4-7, n0-1)
    READ_A(1);
    if (kt + 2 < NT) STAGE_B(cur, 0, kt + 2);
    PHASE_SYNC();
    MFMA_Q(1, 0);
    __builtin_amdgcn_s_barrier();
    // ---- q3: quadrant (m4-7, n2-3)
    if (kt + 2 < NT) STAGE_B(cur, 1, kt + 2);
    PHASE_SYNC();
    MFMA_Q(1, 1);
    if (kt + 1 < NT) {
      if (kt + 2 < NT) asm volatile("s_waitcnt vmcnt(4)" ::: "memory");
      else             asm volatile("s_waitcnt vmcnt(0)" ::: "memory");
    }
    __builtin_amdgcn_s_barrier();
  }

  // epilogue: D layout col = lane&15, row = (lane>>4)*4 + i
  const int seg = bn >> 9;
  const float* bp = bias;
  if (EPI == 4) bp = (seg == 0) ? bias : ((seg == 1) ? bias2 : bias3);
#pragma unroll
  for (int m = 0; m < 8; ++m) {
    int row0 = bm + wr * 128 + m * 16 + (lane >> 4) * 4;
#pragma unroll
    for (int n = 0; n < 4; ++n) {
      int col = bn + wc * 64 + n * 16 + rl;
      float bc = (EPI >= 1) ? bp[(EPI == 4) ? (col & 511) : col] : 0.f;
#pragma unroll
      for (int i = 0; i < 4; ++i) {
        float v = acc[m][n][i];
        if (EPI == 1) v += bc;
        if (EPI == 4) {
          v += bc;
          v = (seg == 0) ? tanhf(v) : 1.f / (1.f + __expf(-v));
        }
        C[(size_t)(row0 + i) * N + col] = f2bf(v);
      }
    }
  }
}

// ---------------------------------------------------------------------------
// K5: in-place row softmax over 1024 bf16 scores, one block per row
__global__ __launch_bounds__(256) void softmax_rows(unsigned short* __restrict__ Sb) {
  __shared__ float red[8];
  unsigned short* p = Sb + (size_t)blockIdx.x * S_LEN;
  int t = threadIdx.x, wave = t >> 6, lane = t & 63;
  ushort4 u = *(ushort4*)(p + t * 4);
  float v0 = bf2f(u.x), v1 = bf2f(u.y), v2 = bf2f(u.z), v3 = bf2f(u.w);
  float mx = fmaxf(fmaxf(v0, v1), fmaxf(v2, v3));
#pragma unroll
  for (int o = 32; o; o >>= 1) mx = fmaxf(mx, __shfl_xor(mx, o));
  if (lane == 0) red[wave] = mx;
  __syncthreads();
  mx = fmaxf(fmaxf(red[0], red[1]), fmaxf(red[2], red[3]));
  float e0 = __expf(v0 - mx), e1 = __expf(v1 - mx);
  float e2 = __expf(v2 - mx), e3 = __expf(v3 - mx);
  float ss = e0 + e1 + e2 + e3;
#pragma unroll
  for (int o = 32; o; o >>= 1) ss += __shfl_xor(ss, o);
  if (lane == 0) red[4 + wave] = ss;
  __syncthreads();
  float inv = 1.f / (red[4] + red[5] + red[6] + red[7]);
  u.x = f2bf(e0 * inv); u.y = f2bf(e1 * inv);
  u.z = f2bf(e2 * inv); u.w = f2bf(e3 * inv);
  *(ushort4*)(p + t * 4) = u;
}

// ---------------------------------------------------------------------------
// K8: out = r*P + f*z  reading fused MLP output Cm[16384][1536] = [z|r|f]
__global__ __launch_bounds__(256) void final_out(
    const float* __restrict__ P, const unsigned short* __restrict__ Cm,
    float* __restrict__ out) {
  size_t i = ((size_t)blockIdx.x * 256 + threadIdx.x) * 4;
  size_t row = i >> 9;
  int col = (int)(i & 511);
  const unsigned short* base = Cm + row * 1536 + col;
  ushort4 z4 = *(const ushort4*)(base);
  ushort4 r4 = *(const ushort4*)(base + 512);
  ushort4 f4 = *(const ushort4*)(base + 1024);
  float4 p = *(const float4*)(P + i);
  float4 o;
  o.x = bf2f(r4.x) * p.x + bf2f(f4.x) * bf2f(z4.x);
  o.y = bf2f(r4.y) * p.y + bf2f(f4.y) * bf2f(z4.y);
  o.z = bf2f(r4.z) * p.z + bf2f(f4.z) * bf2f(z4.z);
  o.w = bf2f(r4.w) * p.w + bf2f(f4.w) * bf2f(z4.w);
  *(float4*)(out + i) = o;
}

// ---------------------------------------------------------------------------
extern "C" void kernel_launch(void* const* d_in, const int* in_sizes, int n_in,
                              void* d_out, int out_size, void* d_ws, size_t ws_size,
                              hipStream_t stream) {
  const float* P  = (const float*)d_in[0];
  const float* wa = (const float*)d_in[1];
  const float* w1 = (const float*)d_in[2];
  const float* w2 = (const float*)d_in[3];
  const float* w3 = (const float*)d_in[4];
  const float* b1 = (const float*)d_in[5];
  const float* b2 = (const float*)d_in[6];
  const float* b3 = (const float*)d_in[7];
  float* out = (float*)d_out;
  char* ws = (char*)d_ws;
  const size_t MB = 1024 * 1024;

  unsigned short* Pbf  = (unsigned short*)(ws + 0);        // 16 MB, live to end
  unsigned short* PT   = (unsigned short*)(ws + 16 * MB);  // 16 MB, dead after PV
  unsigned short* Qbf  = (unsigned short*)(ws + 32 * MB);  // 16 MB, dead after scores
  unsigned short* Sbuf = (unsigned short*)(ws + 48 * MB);  // 32 MB, dead after PV
  unsigned short* attn = (unsigned short*)(ws + 80 * MB);  // 16 MB
  unsigned short* Wt   = (unsigned short*)(ws + 96 * MB);  // 3 MB  [1536][1024]
  float*          sj   = (float*)(ws + 99 * MB);           // 64 KB
  unsigned short* Cmlp = (unsigned short*)(ws + 16 * MB);  // 48 MB, reuse PT+Qbf+Sbuf

  const long SD = (long)S_LEN * DDIM;        // 1024*512
  const long SS = (long)S_LEN * S_LEN;       // 1024*1024

  prep_rows<<<4096, 256, 0, stream>>>(P, wa, Pbf, Qbf, sj);
  transpose_f2b<<<dim3(8, 16, NBATCH), 256, 0, stream>>>(P, PT, S_LEN, DDIM, SD, SD);
  transpose_f2b<<<dim3(8, 16, 1), 256, 0, stream>>>(w1, Wt,          1024, 512, 0, 0);
  transpose_f2b<<<dim3(8, 16, 1), 256, 0, stream>>>(w2, Wt + SD,     1024, 512, 0, 0);
  transpose_f2b<<<dim3(8, 16, 1), 256, 0, stream>>>(w3, Wt + 2 * SD, 1024, 512, 0, 0);

  // scores: S[b] = Qbf[b] @ Pbf[b]^T + sj[b][col]   (M=N=1024, K=512)
  gemm8<1><<<dim3(4, 4, NBATCH), 512, 0, stream>>>(
      Qbf, nullptr, Pbf, Sbuf, sj, nullptr, nullptr,
      1024, 512, 512, 0, SD, SD, SS, S_LEN);
  softmax_rows<<<16384, 256, 0, stream>>>(Sbuf);
  // attn[b] = SA[b] @ PT[b]^T   (M=1024, N=512, K=1024)
  gemm8<0><<<dim3(2, 4, NBATCH), 512, 0, stream>>>(
      Sbuf, nullptr, PT, attn, nullptr, nullptr, nullptr,
      512, 1024, 1024, 0, SS, SD, SD, 0);
  // fused MLP: Cmlp[16384][1536] = [Pbf|attn] @ [w1t|w2t|w3t]^T (+bias, act)
  gemm8<4><<<dim3(6, 64, 1), 512, 0, stream>>>(
      Pbf, attn, Wt, Cmlp, b1, b2, b3,
      1536, 1024, 512, 512, 0, 0, 0, 0);

  final_out<<<8192, 256, 0, stream>>>(P, Cmlp, out);
}

// Round 4
// 212.188 us; speedup vs baseline: 1.0293x; 1.0293x over previous
//
#include <hip/hip_runtime.h>
#include <stdint.h>

#define S_LEN 1024
#define DDIM  512
#define NBATCH 16

typedef __attribute__((ext_vector_type(8))) short bf16x8;
typedef __attribute__((ext_vector_type(4))) float f32x4;
typedef unsigned short ushort_t;

__device__ __forceinline__ unsigned short f2bf(float x) {
  union { float f; uint32_t u; } v; v.f = x;
  return (unsigned short)((v.u + 0x7fffu + ((v.u >> 16) & 1u)) >> 16);
}
__device__ __forceinline__ float bf2f(unsigned short h) {
  union { float f; uint32_t u; } v; v.u = ((uint32_t)h) << 16;
  return v.f;
}

__device__ __forceinline__ void gload16(const void* g, void* l) {
  __builtin_amdgcn_global_load_lds(
      (const __attribute__((address_space(1))) void*)g,
      (__attribute__((address_space(3))) void*)l, 16, 0, 0);
}

// ---------------------------------------------------------------------------
// K1: per-row prep: sj[row] = P[row,:]·wb ; Pbf = bf16(P) ; Qbf = bf16(P*wc)
__global__ __launch_bounds__(256) void prep_rows(
    const float* __restrict__ P, const float* __restrict__ w_atten,
    unsigned short* __restrict__ Pbf, unsigned short* __restrict__ Qbf,
    float* __restrict__ sj) {
  int wave = threadIdx.x >> 6, lane = threadIdx.x & 63;
  int row = blockIdx.x * 4 + wave;
  const float* prow = P + (size_t)row * DDIM;
  float s = 0.f;
#pragma unroll
  for (int h = 0; h < 2; ++h) {
    int d = h * 256 + lane * 4;
    float4 p  = *(const float4*)(prow + d);
    float4 wb = *(const float4*)(w_atten + DDIM + d);
    float4 wc = *(const float4*)(w_atten + 2 * DDIM + d);
    s += p.x * wb.x + p.y * wb.y + p.z * wb.z + p.w * wb.w;
    ushort4 pb, qb;
    pb.x = f2bf(p.x); pb.y = f2bf(p.y); pb.z = f2bf(p.z); pb.w = f2bf(p.w);
    qb.x = f2bf(p.x * wc.x); qb.y = f2bf(p.y * wc.y);
    qb.z = f2bf(p.z * wc.z); qb.w = f2bf(p.w * wc.w);
    *(ushort4*)(Pbf + (size_t)row * DDIM + d) = pb;
    *(ushort4*)(Qbf + (size_t)row * DDIM + d) = qb;
  }
#pragma unroll
  for (int o = 32; o; o >>= 1) s += __shfl_xor(s, o);
  if (lane == 0) sj[row] = s;
}

// ---------------------------------------------------------------------------
// K2: tiled transpose fp32[R][C] -> bf16[C][R]   (64x64 tiles)
__global__ __launch_bounds__(256) void transpose_f2b(
    const float* __restrict__ in, unsigned short* __restrict__ out,
    int R, int C, long inStride, long outStride) {
  __shared__ unsigned short T[64][65];
  in  += (size_t)blockIdx.z * inStride;
  out += (size_t)blockIdx.z * outStride;
  int c0 = blockIdx.x * 64, r0 = blockIdx.y * 64;
  int tx = threadIdx.x & 63, ty = threadIdx.x >> 6;
#pragma unroll
  for (int rr = 0; rr < 16; ++rr) {
    int rl = ty * 16 + rr;
    T[rl][tx] = f2bf(in[(size_t)(r0 + rl) * C + c0 + tx]);
  }
  __syncthreads();
#pragma unroll
  for (int rr = 0; rr < 16; ++rr) {
    int cl = ty * 16 + rr;
    out[(size_t)(c0 + cl) * R + r0 + tx] = T[tx][cl];
  }
}

// ---------------------------------------------------------------------------
// 8-phase 256x256 bf16 NT GEMM (T1+T2+T3+T4+T5), BK=64, 8 waves (2M x 4N).
#define STAGE_A(buf, h, kt_) do { int k0_ = (kt_) * 64; const ushort_t* s_ = A;   \
    if (A2 != nullptr && k0_ >= Ksplit) { s_ = A2; k0_ -= Ksplit; }               \
    ushort_t* d_ = &lds[((buf) * 2 + (h)) * 8192 + w * 1024];                     \
    const ushort_t* g_ = s_ + (size_t)(bm + (h) * 128 + srow) * lda + k0_ + scol; \
    gload16(g_, d_); gload16(g_ + 32, d_ + 512); } while (0)

#define STAGE_B(buf, h, kt_) do { int k0_ = (kt_) * 64;                           \
    ushort_t* d_ = &lds[32768 + ((buf) * 2 + (h)) * 8192 + w * 1024];             \
    const ushort_t* g_ = Bt + (size_t)(bn + (h) * 128 + srow) * K + k0_ + scol;   \
    gload16(g_, d_); gload16(g_ + 32, d_ + 512); } while (0)

#define READ_A(mh) do { const char* ab_ = (const char*)&lds[(cur * 2 + wr) * 8192]; \
    _Pragma("unroll") for (int m_ = 0; m_ < 4; ++m_)                                \
    _Pragma("unroll") for (int ks_ = 0; ks_ < 2; ++ks_)                             \
      af[m_][ks_] = *(const bf16x8*)(ab_ + ((((mh) * 4 + m_) * 2 + ks_) << 10)      \
                                     + rl * 64 + swzc); } while (0)

#define READ_B(nh) do { const char* bb_ = (const char*)&lds[32768 + (cur * 2 + (wc >> 1)) * 8192]; \
    _Pragma("unroll") for (int n_ = 0; n_ < 2; ++n_)                                \
    _Pragma("unroll") for (int ks_ = 0; ks_ < 2; ++ks_)                             \
      bfr[(nh) * 2 + n_][ks_] = *(const bf16x8*)(bb_ +                              \
          ((((wc & 1) * 4 + (nh) * 2 + n_) * 2 + ks_) << 10) + rl * 64 + swzc); } while (0)

#define MFMA_Q(mh, nh) do {                                                       \
    __builtin_amdgcn_s_setprio(1);                                                \
    _Pragma("unroll") for (int m_ = 0; m_ < 4; ++m_)                              \
    _Pragma("unroll") for (int n_ = 0; n_ < 2; ++n_) {                            \
      f32x4 a_ = acc[(mh) * 4 + m_][(nh) * 2 + n_];                               \
      a_ = __builtin_amdgcn_mfma_f32_16x16x32_bf16(af[m_][0], bfr[(nh)*2+n_][0], a_, 0, 0, 0); \
      a_ = __builtin_amdgcn_mfma_f32_16x16x32_bf16(af[m_][1], bfr[(nh)*2+n_][1], a_, 0, 0, 0); \
      acc[(mh) * 4 + m_][(nh) * 2 + n_] = a_; }                                   \
    __builtin_amdgcn_s_setprio(0); } while (0)

#define PHASE_SYNC() do { __builtin_amdgcn_s_barrier();                           \
    asm volatile("s_waitcnt lgkmcnt(0)" ::: "memory");                            \
    __builtin_amdgcn_sched_barrier(0); } while (0)

template<int EPI>
__global__ __launch_bounds__(512, 2) void gemm8(
    const ushort_t* __restrict__ A,
    const ushort_t* __restrict__ A2,
    const ushort_t* __restrict__ Bt,
    ushort_t* __restrict__ C,
    const float* __restrict__ bias,
    const float* __restrict__ bias2,
    const float* __restrict__ bias3,
    int N, int K, int lda, int Ksplit,
    long sAb, long sBb, long sCb, long sBiasb) {
  __shared__ __align__(16) ushort_t lds[65536];   // 128 KiB
  const int t = threadIdx.x, lane = t & 63, w = t >> 6;
  const int wr = w >> 2, wc = w & 3;

  // T1 bijective XCD swizzle (all grids have total % 8 == 0; x-fastest
  // linearization keeps same-A-strip blocks on one XCD).
  const int gx = gridDim.x, gy = gridDim.y;
  int hblk = blockIdx.x + gx * (blockIdx.y + gy * blockIdx.z);
  int cpx = (gx * gy * (int)gridDim.z) >> 3;
  int wk = (hblk & 7) * cpx + (hblk >> 3);
  const int bx = wk % gx; int rem = wk / gx;
  const int by = rem % gy;
  const int z  = rem / gy;

  A += (size_t)z * sAb;
  if (A2) A2 += (size_t)z * sAb;
  Bt += (size_t)z * sBb;
  C += (size_t)z * sCb;
  if (bias) bias += (size_t)z * sBiasb;
  const int bm = by * 256, bn = bx * 256;
  const int NT = K >> 6;

  const int rl = lane & 15;
  const int swzc = ((lane >> 4) << 4) ^ ((lane & 8) << 2);
  const int srow = w * 16 + (lane >> 2);
  const int scol = ((lane & 3) * 8) ^ ((lane & 32) >> 1);

  f32x4 acc[8][4];
#pragma unroll
  for (int m = 0; m < 8; ++m)
#pragma unroll
    for (int n = 0; n < 4; ++n) acc[m][n] = {0.f, 0.f, 0.f, 0.f};
  bf16x8 af[4][2], bfr[4][2];

  STAGE_A(0, 0, 0); STAGE_A(0, 1, 0);
  STAGE_B(0, 0, 0); STAGE_B(0, 1, 0);
  STAGE_B(1, 0, 1); STAGE_B(1, 1, 1);
  asm volatile("s_waitcnt vmcnt(4)" ::: "memory");
  __builtin_amdgcn_s_barrier();

  for (int kt = 0; kt < NT; ++kt) {
    const int cur = kt & 1, nxt = cur ^ 1;
    READ_A(0); READ_B(0);
    if (kt + 1 < NT) STAGE_A(nxt, 0, kt + 1);
    PHASE_SYNC();
    MFMA_Q(0, 0);
    __builtin_amdgcn_s_barrier();
    READ_B(1);
    if (kt + 1 < NT) STAGE_A(nxt, 1, kt + 1);
    PHASE_SYNC();
    MFMA_Q(0, 1);
    __builtin_amdgcn_s_barrier();
    READ_A(1);
    if (kt + 2 < NT) STAGE_B(cur, 0, kt + 2);
    PHASE_SYNC();
    MFMA_Q(1, 0);
    __builtin_amdgcn_s_barrier();
    if (kt + 2 < NT) STAGE_B(cur, 1, kt + 2);
    PHASE_SYNC();
    MFMA_Q(1, 1);
    if (kt + 1 < NT) {
      if (kt + 2 < NT) asm volatile("s_waitcnt vmcnt(4)" ::: "memory");
      else             asm volatile("s_waitcnt vmcnt(0)" ::: "memory");
    }
    __builtin_amdgcn_s_barrier();
  }

  const int seg = bn >> 9;
  const float* bp = bias;
  if (EPI == 4) bp = (seg == 0) ? bias : ((seg == 1) ? bias2 : bias3);
#pragma unroll
  for (int m = 0; m < 8; ++m) {
    int row0 = bm + wr * 128 + m * 16 + (lane >> 4) * 4;
#pragma unroll
    for (int n = 0; n < 4; ++n) {
      int col = bn + wc * 64 + n * 16 + rl;
      float bc = (EPI >= 1) ? bp[(EPI == 4) ? (col & 511) : col] : 0.f;
#pragma unroll
      for (int i = 0; i < 4; ++i) {
        float v = acc[m][n][i];
        if (EPI == 1) v += bc;
        if (EPI == 4) {
          v += bc;
          v = (seg == 0) ? tanhf(v) : 1.f / (1.f + __expf(-v));
        }
        C[(size_t)(row0 + i) * N + col] = f2bf(v);
      }
    }
  }
}

// ---------------------------------------------------------------------------
// 2-phase double-buffered 128x128 NT GEMM (R2-proven) — used for PV.
template<int EPI>
__global__ __launch_bounds__(256) void gemm_nt(
    const unsigned short* __restrict__ A,
    const unsigned short* __restrict__ A2,
    const unsigned short* __restrict__ Bt,
    unsigned short* __restrict__ C,
    const float* __restrict__ bias,
    int N, int K, int lda, int Ksplit,
    long sAb, long sBb, long sCb, long sBiasb) {
  __shared__ __align__(16) unsigned short lA[2][128 * 32];
  __shared__ __align__(16) unsigned short lB[2][128 * 32];
  const int t = threadIdx.x;
  const int lane = t & 63;
  const int wave = t >> 6;
  const int z = blockIdx.z;
  A  += (size_t)z * sAb;
  if (A2) A2 += (size_t)z * sAb;
  Bt += (size_t)z * sBb;
  C  += (size_t)z * sCb;
  if (bias) bias += (size_t)z * sBiasb;
  const int bm = blockIdx.y * 128, bn = blockIdx.x * 128;

  f32x4 acc[4][4];
#pragma unroll
  for (int m = 0; m < 4; ++m)
#pragma unroll
    for (int n = 0; n < 4; ++n) acc[m][n] = {0.f, 0.f, 0.f, 0.f};

  const int wr = wave >> 1, wc = wave & 1;
  const int frow = lane & 15;
  const int fk = (lane >> 4) * 8;
  const int srow = t >> 2;
  const int skc = (t & 3) * 8;
  const int lbase = (t & 192) * 8;

  auto stage = [&](int buf, int k0) {
    const unsigned short* Asrc = A;
    int ka = k0;
    if (A2 != nullptr && k0 >= Ksplit) { Asrc = A2; ka = k0 - Ksplit; }
#pragma unroll
    for (int r2 = 0; r2 < 2; ++r2)
      gload16(Asrc + (size_t)(bm + r2 * 64 + srow) * lda + ka + skc,
              lA[buf] + r2 * 2048 + lbase);
#pragma unroll
    for (int r2 = 0; r2 < 2; ++r2)
      gload16(Bt + (size_t)(bn + r2 * 64 + srow) * K + k0 + skc,
              lB[buf] + r2 * 2048 + lbase);
  };

  stage(0, 0);
  __syncthreads();
  int cur = 0;
  for (int k0 = 0; k0 < K; k0 += 32) {
    if (k0 + 32 < K) stage(cur ^ 1, k0 + 32);
    bf16x8 af[4], bfr[4];
#pragma unroll
    for (int m = 0; m < 4; ++m)
      af[m] = *(const bf16x8*)(lA[cur] + (wr * 64 + m * 16 + frow) * 32 + fk);
#pragma unroll
    for (int n = 0; n < 4; ++n)
      bfr[n] = *(const bf16x8*)(lB[cur] + (wc * 64 + n * 16 + frow) * 32 + fk);
#pragma unroll
    for (int m = 0; m < 4; ++m)
#pragma unroll
      for (int n = 0; n < 4; ++n)
        acc[m][n] = __builtin_amdgcn_mfma_f32_16x16x32_bf16(af[m], bfr[n], acc[m][n], 0, 0, 0);
    __syncthreads();
    cur ^= 1;
  }

#pragma unroll
  for (int m = 0; m < 4; ++m) {
    int row0 = bm + wr * 64 + m * 16 + (lane >> 4) * 4;
#pragma unroll
    for (int n = 0; n < 4; ++n) {
      int col = bn + wc * 64 + n * 16 + (lane & 15);
      float bc = (EPI >= 1) ? bias[col] : 0.f;
#pragma unroll
      for (int i = 0; i < 4; ++i) {
        float v = acc[m][n][i];
        if (EPI == 1) v += bc;
        C[(size_t)(row0 + i) * N + col] = f2bf(v);
      }
    }
  }
}

// ---------------------------------------------------------------------------
// K5: in-place row softmax over 1024 bf16 scores, one block per row
__global__ __launch_bounds__(256) void softmax_rows(unsigned short* __restrict__ Sb) {
  __shared__ float red[8];
  unsigned short* p = Sb + (size_t)blockIdx.x * S_LEN;
  int t = threadIdx.x, wave = t >> 6, lane = t & 63;
  ushort4 u = *(ushort4*)(p + t * 4);
  float v0 = bf2f(u.x), v1 = bf2f(u.y), v2 = bf2f(u.z), v3 = bf2f(u.w);
  float mx = fmaxf(fmaxf(v0, v1), fmaxf(v2, v3));
#pragma unroll
  for (int o = 32; o; o >>= 1) mx = fmaxf(mx, __shfl_xor(mx, o));
  if (lane == 0) red[wave] = mx;
  __syncthreads();
  mx = fmaxf(fmaxf(red[0], red[1]), fmaxf(red[2], red[3]));
  float e0 = __expf(v0 - mx), e1 = __expf(v1 - mx);
  float e2 = __expf(v2 - mx), e3 = __expf(v3 - mx);
  float ss = e0 + e1 + e2 + e3;
#pragma unroll
  for (int o = 32; o; o >>= 1) ss += __shfl_xor(ss, o);
  if (lane == 0) red[4 + wave] = ss;
  __syncthreads();
  float inv = 1.f / (red[4] + red[5] + red[6] + red[7]);
  u.x = f2bf(e0 * inv); u.y = f2bf(e1 * inv);
  u.z = f2bf(e2 * inv); u.w = f2bf(e3 * inv);
  *(ushort4*)(p + t * 4) = u;
}

// ---------------------------------------------------------------------------
// K8: out = r*P + f*z  reading fused MLP output Cm[16384][1536] = [z|r|f]
__global__ __launch_bounds__(256) void final_out(
    const float* __restrict__ P, const unsigned short* __restrict__ Cm,
    float* __restrict__ out) {
  size_t i = ((size_t)blockIdx.x * 256 + threadIdx.x) * 4;
  size_t row = i >> 9;
  int col = (int)(i & 511);
  const unsigned short* base = Cm + row * 1536 + col;
  ushort4 z4 = *(const ushort4*)(base);
  ushort4 r4 = *(const ushort4*)(base + 512);
  ushort4 f4 = *(const ushort4*)(base + 1024);
  float4 p = *(const float4*)(P + i);
  float4 o;
  o.x = bf2f(r4.x) * p.x + bf2f(f4.x) * bf2f(z4.x);
  o.y = bf2f(r4.y) * p.y + bf2f(f4.y) * bf2f(z4.y);
  o.z = bf2f(r4.z) * p.z + bf2f(f4.z) * bf2f(z4.z);
  o.w = bf2f(r4.w) * p.w + bf2f(f4.w) * bf2f(z4.w);
  *(float4*)(out + i) = o;
}

// ---------------------------------------------------------------------------
extern "C" void kernel_launch(void* const* d_in, const int* in_sizes, int n_in,
                              void* d_out, int out_size, void* d_ws, size_t ws_size,
                              hipStream_t stream) {
  const float* P  = (const float*)d_in[0];
  const float* wa = (const float*)d_in[1];
  const float* w1 = (const float*)d_in[2];
  const float* w2 = (const float*)d_in[3];
  const float* w3 = (const float*)d_in[4];
  const float* b1 = (const float*)d_in[5];
  const float* b2 = (const float*)d_in[6];
  const float* b3 = (const float*)d_in[7];
  float* out = (float*)d_out;
  char* ws = (char*)d_ws;
  const size_t MB = 1024 * 1024;

  unsigned short* Pbf  = (unsigned short*)(ws + 0);        // 16 MB, live to end
  unsigned short* PT   = (unsigned short*)(ws + 16 * MB);  // 16 MB, dead after PV
  unsigned short* Qbf  = (unsigned short*)(ws + 32 * MB);  // 16 MB, dead after scores
  unsigned short* Sbuf = (unsigned short*)(ws + 48 * MB);  // 32 MB, dead after PV
  unsigned short* attn = (unsigned short*)(ws + 80 * MB);  // 16 MB
  unsigned short* Wt   = (unsigned short*)(ws + 96 * MB);  // 3 MB  [1536][1024]
  float*          sj   = (float*)(ws + 99 * MB);           // 64 KB
  unsigned short* Cmlp = (unsigned short*)(ws + 16 * MB);  // 48 MB, reuse PT+Qbf+Sbuf

  const long SD = (long)S_LEN * DDIM;
  const long SS = (long)S_LEN * S_LEN;

  prep_rows<<<4096, 256, 0, stream>>>(P, wa, Pbf, Qbf, sj);
  transpose_f2b<<<dim3(8, 16, NBATCH), 256, 0, stream>>>(P, PT, S_LEN, DDIM, SD, SD);
  transpose_f2b<<<dim3(8, 16, 1), 256, 0, stream>>>(w1, Wt,          1024, 512, 0, 0);
  transpose_f2b<<<dim3(8, 16, 1), 256, 0, stream>>>(w2, Wt + SD,     1024, 512, 0, 0);
  transpose_f2b<<<dim3(8, 16, 1), 256, 0, stream>>>(w3, Wt + 2 * SD, 1024, 512, 0, 0);

  // scores: S[b] = Qbf[b] @ Pbf[b]^T + sj[b][col]   (M=N=1024, K=512)
  gemm8<1><<<dim3(4, 4, NBATCH), 512, 0, stream>>>(
      Qbf, nullptr, Pbf, Sbuf, sj, nullptr, nullptr,
      1024, 512, 512, 0, SD, SD, SS, S_LEN);
  softmax_rows<<<16384, 256, 0, stream>>>(Sbuf);
  // attn[b] = SA[b] @ PT[b]^T  (M=1024, N=512, K=1024) — 2-phase, 512 blocks
  gemm_nt<0><<<dim3(4, 8, NBATCH), 256, 0, stream>>>(
      Sbuf, nullptr, PT, attn, nullptr,
      512, 1024, 1024, 0, SS, SD, SD, 0);
  // fused MLP: Cmlp[16384][1536] = [Pbf|attn] @ [w1t|w2t|w3t]^T (+bias, act)
  gemm8<4><<<dim3(6, 64, 1), 512, 0, stream>>>(
      Pbf, attn, Wt, Cmlp, b1, b2, b3,
      1536, 1024, 512, 512, 0, 0, 0, 0);

  final_out<<<8192, 256, 0, stream>>>(P, Cmlp, out);
}